// Round 19
// baseline (477.195 us; speedup 1.0000x reference)
//
#include <hip/hip_runtime.h>

// FNO spectral block: x(32,256,4096), weight(256,256,128,2) -> out (dtype of x).
// probe -> basis -> fwd gemm (radix-2 folded rDFT, fused pack to mode-major
// Xm[m][b][i] u32(re,im)) -> mixm (per-mode MFMA complex GEMM, W streamed to
// LDS as bf16 with pre-negated Wim) -> inv gemm (radix-2 folded irDFT,
// butterfly epilogue).

typedef unsigned short u16;
typedef unsigned int   u32;
typedef __attribute__((ext_vector_type(8))) short bf16x8;
typedef __attribute__((ext_vector_type(4))) float f32x4;

#define MLEN  4096

__device__ __forceinline__ u16 f2b(float f) {           // fp32 -> bf16 RNE
  u32 u = __float_as_uint(f);
  u += 0x7fffu + ((u >> 16) & 1u);
  return (u16)(u >> 16);
}
__device__ __forceinline__ float blo(u32 p) { return __uint_as_float(p << 16); }
__device__ __forceinline__ float bhi(u32 p) { return __uint_as_float(p & 0xffff0000u); }

// ------------------------------------------------------------- dtype probe
__global__ void probe_kernel(const u16* __restrict__ x16, int* __restrict__ flag) {
  __shared__ int cnt;
  if (threadIdx.x == 0) cnt = 0;
  __syncthreads();
  int c = 0;
  for (int j = threadIdx.x; j < 4096; j += 256) {
    u32 e = (x16[j] >> 7) & 0xFFu;
    if (e >= 0x8Fu) ++c;
  }
  atomicAdd(&cnt, c);
  __syncthreads();
  if (threadIdx.x == 0) flag[0] = (cnt > 256) ? 0 : 1;   // 0=fp32, 1=bf16
}

// ---------------------------------------------------------------- basis
__global__ void basis_kernel(u16* __restrict__ Bas1P, u16* __restrict__ Bas2P) {
  int t = blockIdx.x;           // 0..2047
  int c = threadIdx.x;          // 0..255
  {
    int p = c >> 7, rem = c & 127, j = rem >> 1, s2 = rem & 1;
    int m = 2 * j + p;
    int idx = (m * t) & 4095;
    float theta = (float)idx * (6.283185307179586f / 4096.0f);
    float s, cth;
    __sincosf(theta, &s, &cth);
    Bas2P[t * 256 + c] = f2b(s2 ? -s : cth);
  }
  {
    int parity = c >> 7, isim = (c >> 6) & 1, j = c & 63;
    int m = 2 * j + parity;
    int idx = (m * t) & 4095;
    float theta = (float)idx * (6.283185307179586f / 4096.0f);
    float s, cth;
    __sincosf(theta, &s, &cth);
    Bas1P[c * 2048 + t] = f2b(isim ? -s : cth);
  }
}

// ---------------------------------------------------------------- GEMM (NT)
// C = A(MxK,row,lda) * Bt(NxK,row,ldb)^T.
// EPI=1: radix-2 inverse. K=256: kt<128 -> accE (even modes), kt>=128 -> accO.
//        Epilogue butterfly: out[t']=x+lrelu(E+O), out[t'+2048]=x+lrelu(E-O).
// EPI=2: radix-2 forward: p=blockIdx.z parity; A-load folds x[t] +/- x[t+2048];
//        pack C into mode-major Xm[m][b][i] = u32(re,im), m = 2j+p.
template <int BM, int BN, int EPI, bool ADUAL>
__global__ __launch_bounds__(256)
void gemm_nt(const void* __restrict__ A, const u16* __restrict__ Bt,
             int K, int lda, int ldb,
             u32* __restrict__ Xp, int ldc,
             const void* __restrict__ xres, void* __restrict__ outp,
             const int* __restrict__ flag) {
  constexpr int LD = 72;                 // 64+8 pad: <=2-way LDS conflicts (free)
  constexpr int FM = BM / 32;
  constexpr int FN = BN / 32;
  __shared__ __align__(16) char smem[(BM + BN) * LD * 2];
  u16* As = (u16*)smem;
  u16* Bs = (u16*)(smem + BM * LD * 2);
  const int mode = (ADUAL || EPI == 1) ? flag[0] : 1;
  const int tid = threadIdx.x;
  const int bn0 = blockIdx.x * BN;
  const int bm0 = blockIdx.y * BM;
  const int lane = tid & 63;
  const int wave = tid >> 6;
  const int wm = wave >> 1, wn = wave & 1;
  const int l15 = lane & 15, q4 = lane >> 4;

  const u16* Btb = Bt;
  if constexpr (EPI == 2) Btb += (size_t)blockIdx.z * BN * ldb;

  f32x4 acc[FM][FN] = {};    // EPI==1: even-mode accumulator E
  f32x4 acc2[FM][FN] = {};   // EPI==1: odd-mode accumulator O (else unused/DCE)

  // one 64-wide K-step of MFMAs into the given accumulator (static indexing)
  auto kstep = [&](f32x4 (&ac)[FM][FN]) {
#pragma unroll
    for (int kk = 0; kk < 2; ++kk) {
      const int ko = kk * 32 + q4 * 8;
      bf16x8 af[FM], bfr[FN];
#pragma unroll
      for (int mi = 0; mi < FM; ++mi)
        af[mi] = *(const bf16x8*)&As[(wm * (BM / 2) + mi * 16 + l15) * LD + ko];
#pragma unroll
      for (int ni = 0; ni < FN; ++ni)
        bfr[ni] = *(const bf16x8*)&Bs[(wn * (BN / 2) + ni * 16 + l15) * LD + ko];
#pragma unroll
      for (int mi = 0; mi < FM; ++mi)
#pragma unroll
        for (int ni = 0; ni < FN; ++ni)
          ac[mi][ni] = __builtin_amdgcn_mfma_f32_16x16x32_bf16(
              af[mi], bfr[ni], ac[mi][ni], 0, 0, 0);
    }
  };

  for (int kt = 0; kt < K; kt += 64) {
    __syncthreads();
    if constexpr (EPI == 2) {
      // radix-2 fold: a = x[row][kt+c] +/- x[row][kt+2048+c]
      const int neg = blockIdx.z;
#pragma unroll
      for (int q = tid; q < BM * 8; q += 256) {
        int row = q >> 3, c8 = q & 7;
        u16 tmp[8];
        if (mode == 1) {
          const u16* s0 = &((const u16*)A)[(size_t)(bm0 + row) * lda + kt + c8 * 8];
          uint4 a0 = *(const uint4*)s0;
          uint4 a1 = *(const uint4*)(s0 + 2048);
          u32 aw[4] = {a0.x, a0.y, a0.z, a0.w};
          u32 bw[4] = {a1.x, a1.y, a1.z, a1.w};
#pragma unroll
          for (int j = 0; j < 4; ++j) {
            float lo = neg ? (blo(aw[j]) - blo(bw[j])) : (blo(aw[j]) + blo(bw[j]));
            float hi = neg ? (bhi(aw[j]) - bhi(bw[j])) : (bhi(aw[j]) + bhi(bw[j]));
            tmp[2 * j]     = f2b(lo);
            tmp[2 * j + 1] = f2b(hi);
          }
        } else {
          const float* s0 = &((const float*)A)[(size_t)(bm0 + row) * lda + kt + c8 * 8];
          float4 f0 = *(const float4*)s0;
          float4 f1 = *(const float4*)(s0 + 4);
          float4 g0 = *(const float4*)(s0 + 2048);
          float4 g1 = *(const float4*)(s0 + 2052);
          float a[8] = {f0.x, f0.y, f0.z, f0.w, f1.x, f1.y, f1.z, f1.w};
          float b[8] = {g0.x, g0.y, g0.z, g0.w, g1.x, g1.y, g1.z, g1.w};
#pragma unroll
          for (int j = 0; j < 8; ++j)
            tmp[j] = f2b(neg ? (a[j] - b[j]) : (a[j] + b[j]));
        }
        *(uint4*)&As[row * LD + c8 * 8] = *(const uint4*)tmp;
      }
    } else {
      const u16* Ab = (const u16*)A;
#pragma unroll
      for (int q = tid; q < BM * 8; q += 256) {
        int row = q >> 3, c8 = q & 7;
        *(uint4*)&As[row * LD + c8 * 8] =
            *(const uint4*)&Ab[(size_t)(bm0 + row) * lda + kt + c8 * 8];
      }
    }
#pragma unroll
    for (int q = tid; q < BN * 8; q += 256) {
      int row = q >> 3, c8 = q & 7;
      *(uint4*)&Bs[row * LD + c8 * 8] =
          *(const uint4*)&Btb[(size_t)(bn0 + row) * ldb + kt + c8 * 8];
    }
    __syncthreads();
    if constexpr (EPI == 1) {
      if (kt >= 128) kstep(acc2); else kstep(acc);
    } else {
      kstep(acc);
    }
  }

  // --------------- epilogues (smem reused; As/Bs dead after barrier) -------
  if constexpr (EPI == 1) {
    // acc rows: wm*64+mi*16+q4*4+r ; cols: wn*32+ni*16+l15 (BN=64).
    // Butterfly: col t'=bn0+cc gets E+O, col bn0+2048+cc gets E-O.
    float* Cs = (float*)smem;            // [32][136]: 0..67 sum, 68..135 diff
    const int s = tid >> 3;              // 0..31 staged row
    const int c8 = tid & 7;
#pragma unroll
    for (int mi = 0; mi < FM; ++mi) {
      __syncthreads();
#pragma unroll
      for (int ni = 0; ni < FN; ++ni) {
        float* dst = &Cs[(wm * 16 + q4 * 4) * 136 + wn * 32 + ni * 16 + l15];
#pragma unroll
        for (int r = 0; r < 4; ++r) {
          float e = acc[mi][ni][r], o = acc2[mi][ni][r];
          dst[r * 136]      = e + o;
          dst[r * 136 + 68] = e - o;
        }
      }
      __syncthreads();
      const int gr = bm0 + mi * 16 + s + ((s < 16) ? 0 : (BM / 2 - 16));
      if (mode == 1) {
        const u16* xr16 = (const u16*)xres;
        u16* o16 = (u16*)outp;
#pragma unroll
        for (int h = 0; h < 2; ++h) {
          float4 va = *(const float4*)&Cs[s * 136 + h * 68 + c8 * 8];
          float4 vb = *(const float4*)&Cs[s * 136 + h * 68 + c8 * 8 + 4];
          size_t gidx = (size_t)gr * ldc + bn0 + h * 2048 + c8 * 8;
          uint4 xv = *(const uint4*)&xr16[gidx];
          float cv[8] = {va.x, va.y, va.z, va.w, vb.x, vb.y, vb.z, vb.w};
          u32 xw[4] = {xv.x, xv.y, xv.z, xv.w};
          u16 ov[8];
#pragma unroll
          for (int j = 0; j < 4; ++j) {
            float l0 = cv[2 * j]     >= 0.f ? cv[2 * j]     : 0.2f * cv[2 * j];
            float l1 = cv[2 * j + 1] >= 0.f ? cv[2 * j + 1] : 0.2f * cv[2 * j + 1];
            ov[2 * j]     = f2b(blo(xw[j]) + l0);
            ov[2 * j + 1] = f2b(bhi(xw[j]) + l1);
          }
          *(uint4*)&o16[gidx] = *(const uint4*)ov;
        }
      } else {
        const float* xf = (const float*)xres;
        float* of = (float*)outp;
#pragma unroll
        for (int h = 0; h < 2; ++h) {
          float4 v0 = *(const float4*)&Cs[s * 136 + h * 68 + c8 * 8];
          float4 v1 = *(const float4*)&Cs[s * 136 + h * 68 + c8 * 8 + 4];
          size_t gidx = (size_t)gr * ldc + bn0 + h * 2048 + c8 * 8;
          float4 x0 = *(const float4*)&xf[gidx];
          float4 x1 = *(const float4*)&xf[gidx + 4];
          float4 o0, o1;
          o0.x = x0.x + (v0.x >= 0.f ? v0.x : 0.2f * v0.x);
          o0.y = x0.y + (v0.y >= 0.f ? v0.y : 0.2f * v0.y);
          o0.z = x0.z + (v0.z >= 0.f ? v0.z : 0.2f * v0.z);
          o0.w = x0.w + (v0.w >= 0.f ? v0.w : 0.2f * v0.w);
          o1.x = x1.x + (v1.x >= 0.f ? v1.x : 0.2f * v1.x);
          o1.y = x1.y + (v1.y >= 0.f ? v1.y : 0.2f * v1.y);
          o1.z = x1.z + (v1.z >= 0.f ? v1.z : 0.2f * v1.z);
          o1.w = x1.w + (v1.w >= 0.f ? v1.w : 0.2f * v1.w);
          *(float4*)&of[gidx] = o0;
          *(float4*)&of[gidx + 4] = o1;
        }
      }
    }
  } else {
    // EPI==2: BM=32 (FM=1), BN=128. Ls cols c<64 -> Re(mode 2c+p), c>=64 -> Im.
    // Write mode-major: Xm[m=2j+p][b][ic0+ic] = u32(re,im); per j, 4 threads
    // cover 32 consecutive ic (128 B contiguous).
    constexpr int LP = 136;              // 128+8 pad
    u16* Ls = (u16*)smem;                // [32][136] bf16 tile
    __syncthreads();
#pragma unroll
    for (int ni = 0; ni < FN; ++ni) {
      u16* dst = &Ls[(wm * 16 + q4 * 4) * LP + wn * 64 + ni * 16 + l15];
#pragma unroll
      for (int r = 0; r < 4; ++r) dst[r * LP] = f2b(acc[0][ni][r]);
    }
    __syncthreads();
    const int b   = bm0 >> 8;
    const int ic0 = bm0 & 255;
    const int j   = tid >> 2;            // 0..63
    const int icg = tid & 3;             // ic block of 8
    const int mo  = 2 * j + blockIdx.z;
    u32 vals[8];
#pragma unroll
    for (int ii = 0; ii < 8; ++ii) {
      int ic = icg * 8 + ii;
      vals[ii] = (u32)Ls[ic * LP + j] | ((u32)Ls[ic * LP + 64 + j] << 16);
    }
    u32* dst = &Xp[((size_t)mo * 32 + b) * 256 + ic0 + icg * 8];
    *(uint4*)dst       = *(const uint4*)&vals[0];
    *(uint4*)(dst + 4) = *(const uint4*)&vals[4];
  }
}

// ---------------------------------------------------------------- mode mix (MFMA)
// Per block: one (mode m, o-quarter) pair. M=32 b, N=64 o, K=256 ic.
// Yre = Xre*Wre + Xim*(-Wim); Yim = Xre*Wim + Xim*Wre (fp32 MFMA accum).
// X staged once (bf16 Xre/Xim); W streamed per K-chunk of 32 into LDS bf16
// (Win = -Wim via sign-bit flip). Writes Yp layout unchanged (scale folded).
__global__ __launch_bounds__(256)
void mixm_kernel(const u32* __restrict__ Xm, const void* __restrict__ w,
                 u16* __restrict__ Yp, const int* __restrict__ flag) {
  constexpr int XL = 264;   // u16 row stride, X arrays [32][256]
  constexpr int WL = 40;    // u16 row stride, W arrays [64][32]
  __shared__ u16 Xre[32 * XL];
  __shared__ u16 Xim[32 * XL];
  __shared__ u16 Wre[64 * WL];
  __shared__ u16 Wip[64 * WL];
  __shared__ u16 Win[64 * WL];
  const int tid = threadIdx.x;
  const int m  = blockIdx.x;            // mode 0..127
  const int o0 = blockIdx.y * 64;       // o-range base
  const int mode = flag[0];
  const int lane = tid & 63, wv = tid >> 6;
  const int l15 = lane & 15, q4 = lane >> 4;

  // ---- stage X once: Xm[m][b][i] u32(re,im), 32x256 -> Xre/Xim bf16
  {
    const int b = tid >> 3, i0 = (tid & 7) * 32;
    const uint4* src = (const uint4*)(Xm + ((size_t)m * 32 + b) * 256 + i0);
#pragma unroll
    for (int c = 0; c < 8; ++c) {
      uint4 v = src[c];
      int i = i0 + c * 4;
      *(u32*)&Xre[b * XL + i]     = (v.x & 0xffffu) | (v.y << 16);
      *(u32*)&Xre[b * XL + i + 2] = (v.z & 0xffffu) | (v.w << 16);
      *(u32*)&Xim[b * XL + i]     = (v.x >> 16) | (v.y & 0xffff0000u);
      *(u32*)&Xim[b * XL + i + 2] = (v.z >> 16) | (v.w & 0xffff0000u);
    }
  }

  f32x4 accRe[2] = {}, accIm[2] = {};

  const int so = tid >> 2;              // staging o 0..63
  const int sk = (tid & 3) * 8;         // staging k base

  for (int kt = 0; kt < 8; ++kt) {
    const int k0 = kt * 32;
    __syncthreads();
    // ---- stage W chunk [64 o][32 k]
    if (mode == 0) {
      const float* wp = (const float*)w +
          (((size_t)(o0 + so) * 256 + (k0 + sk)) * 128 + m) * 2;
#pragma unroll
      for (int kk = 0; kk < 8; ++kk) {
        float2 f = *(const float2*)(wp + (size_t)kk * 256);
        u16 re = f2b(f.x), im = f2b(f.y);
        Wre[so * WL + sk + kk] = re;
        Wip[so * WL + sk + kk] = im;
        Win[so * WL + sk + kk] = im ^ 0x8000u;
      }
    } else {
      const u32* wp = (const u32*)w +
          ((size_t)(o0 + so) * 256 + (k0 + sk)) * 128 + m;
#pragma unroll
      for (int kk = 0; kk < 8; ++kk) {
        u32 v = wp[(size_t)kk * 128];
        u16 re = (u16)v, im = (u16)(v >> 16);
        Wre[so * WL + sk + kk] = re;
        Wip[so * WL + sk + kk] = im;
        Win[so * WL + sk + kk] = im ^ 0x8000u;
      }
    }
    __syncthreads();
    // ---- MFMA on chunk
    bf16x8 aRe[2], aIm[2];
#pragma unroll
    for (int mi = 0; mi < 2; ++mi) {
      aRe[mi] = *(const bf16x8*)&Xre[(mi * 16 + l15) * XL + k0 + q4 * 8];
      aIm[mi] = *(const bf16x8*)&Xim[(mi * 16 + l15) * XL + k0 + q4 * 8];
    }
    bf16x8 bRe = *(const bf16x8*)&Wre[(wv * 16 + l15) * WL + q4 * 8];
    bf16x8 bIp = *(const bf16x8*)&Wip[(wv * 16 + l15) * WL + q4 * 8];
    bf16x8 bIn = *(const bf16x8*)&Win[(wv * 16 + l15) * WL + q4 * 8];
#pragma unroll
    for (int mi = 0; mi < 2; ++mi) {
      accRe[mi] = __builtin_amdgcn_mfma_f32_16x16x32_bf16(aRe[mi], bRe, accRe[mi], 0, 0, 0);
      accRe[mi] = __builtin_amdgcn_mfma_f32_16x16x32_bf16(aIm[mi], bIn, accRe[mi], 0, 0, 0);
      accIm[mi] = __builtin_amdgcn_mfma_f32_16x16x32_bf16(aRe[mi], bIp, accIm[mi], 0, 0, 0);
      accIm[mi] = __builtin_amdgcn_mfma_f32_16x16x32_bf16(aIm[mi], bRe, accIm[mi], 0, 0, 0);
    }
  }

  // ---- epilogue: Yp32[(b*256+o)*128 + (m&1)*64 + (m>>1)] = (re*sRe | im*sIm<<16)
  const float sIm = 2.0f / 4096.0f;
  const float sRe = (m == 0) ? (1.0f / 4096.0f) : (2.0f / 4096.0f);
  u32* Yp32 = (u32*)Yp;
  const int o = o0 + wv * 16 + l15;
  const int word = (m & 1) * 64 + (m >> 1);
#pragma unroll
  for (int mi = 0; mi < 2; ++mi)
#pragma unroll
    for (int r = 0; r < 4; ++r) {
      int b = mi * 16 + q4 * 4 + r;
      u32 val = (u32)f2b(accRe[mi][r] * sRe) | ((u32)f2b(accIm[mi][r] * sIm) << 16);
      Yp32[((size_t)(b * 256 + o)) * 128 + word] = val;
    }
}

// ---------------------------------------------------------------- launch
extern "C" void kernel_launch(void* const* d_in, const int* in_sizes, int n_in,
                              void* d_out, int out_size, void* d_ws, size_t ws_size,
                              hipStream_t stream) {
  const void* x = d_in[0];                // (32,256,4096) fp32 or bf16
  const void* w = d_in[1];                // (256,256,128,2) fp32 or bf16

  char* ws = (char*)d_ws;
  int*  flag  = (int*)(ws);
  u16*  Bas1P = (u16*)(ws + (1u << 20)); // 1 MB  [r=256][t'=2048] fwd parity
  u16*  Bas2P = (u16*)(ws + (2u << 20)); // 1 MB  [t'=2048][c=256] inv parity
  u32*  Xm    = (u32*)(ws + (4u << 20)); // 4 MB  [m][b][i] u32(re,im)
  u16*  Yp    = (u16*)(ws + (8u << 20)); // 4 MB  parity-grouped (re,im)

  probe_kernel<<<dim3(1), dim3(256), 0, stream>>>((const u16*)x, flag);
  basis_kernel<<<dim3(2048), dim3(256), 0, stream>>>(Bas1P, Bas2P);

  // radix-2 folded forward rDFT: z=parity, K=2048, fused pack into Xm
  gemm_nt<32, 128, 2, true><<<dim3(1, 256, 2), dim3(256), 0, stream>>>(
      x, Bas1P, 2048, MLEN, 2048, Xm, 0, nullptr, nullptr, flag);

  // per-mode MFMA complex channel mix -> Yp (bf16, irfft scaling folded in)
  mixm_kernel<<<dim3(128, 4), dim3(256), 0, stream>>>(Xm, w, Yp, flag);

  // radix-2 folded inverse DFT + LeakyReLU + residual (butterfly epilogue)
  gemm_nt<128, 64, 1, false><<<dim3(32, 64, 1), dim3(256), 0, stream>>>(
      Yp, Bas2P, 256, 256, 256, nullptr, MLEN, x, d_out, flag);
}

// Round 22
// 414.703 us; speedup vs baseline: 1.1507x; 1.1507x over previous
//
#include <hip/hip_runtime.h>

// FNO spectral block: x(32,256,4096), weight(256,256,128,2) -> out (dtype of x).
// probe -> basis -> repack_w (W[o][k][m] -> Wp[m][o][k] u32(bf16 re,im), one
// coalesced pass) -> fwd gemm (radix-2 folded rDFT, pack to mode-major
// Xm[m][b][i]) -> mixm (per-mode MFMA complex GEMM streaming Wp) ->
// inv gemm (radix-2 folded irDFT, butterfly epilogue).

typedef unsigned short u16;
typedef unsigned int   u32;
typedef __attribute__((ext_vector_type(8))) short bf16x8;
typedef __attribute__((ext_vector_type(4))) float f32x4;
typedef __attribute__((ext_vector_type(4))) u32   u32x4;

#define MLEN  4096

__device__ __forceinline__ u16 f2b(float f) {           // fp32 -> bf16 RNE
  u32 u = __float_as_uint(f);
  u += 0x7fffu + ((u >> 16) & 1u);
  return (u16)(u >> 16);
}
__device__ __forceinline__ float blo(u32 p) { return __uint_as_float(p << 16); }
__device__ __forceinline__ float bhi(u32 p) { return __uint_as_float(p & 0xffff0000u); }

// ------------------------------------------------------------- dtype probe
__global__ void probe_kernel(const u16* __restrict__ x16, int* __restrict__ flag) {
  __shared__ int cnt;
  if (threadIdx.x == 0) cnt = 0;
  __syncthreads();
  int c = 0;
  for (int j = threadIdx.x; j < 4096; j += 256) {
    u32 e = (x16[j] >> 7) & 0xFFu;
    if (e >= 0x8Fu) ++c;
  }
  atomicAdd(&cnt, c);
  __syncthreads();
  if (threadIdx.x == 0) flag[0] = (cnt > 256) ? 0 : 1;   // 0=fp32, 1=bf16
}

// ---------------------------------------------------------------- basis
__global__ void basis_kernel(u16* __restrict__ Bas1P, u16* __restrict__ Bas2P) {
  int t = blockIdx.x;           // 0..2047
  int c = threadIdx.x;          // 0..255
  {
    int p = c >> 7, rem = c & 127, j = rem >> 1, s2 = rem & 1;
    int m = 2 * j + p;
    int idx = (m * t) & 4095;
    float theta = (float)idx * (6.283185307179586f / 4096.0f);
    float s, cth;
    __sincosf(theta, &s, &cth);
    Bas2P[t * 256 + c] = f2b(s2 ? -s : cth);
  }
  {
    int parity = c >> 7, isim = (c >> 6) & 1, j = c & 63;
    int m = 2 * j + parity;
    int idx = (m * t) & 4095;
    float theta = (float)idx * (6.283185307179586f / 4096.0f);
    float s, cth;
    __sincosf(theta, &s, &cth);
    Bas1P[c * 2048 + t] = f2b(isim ? -s : cth);
  }
}

// ---------------------------------------------------------------- repack W
// W[o][k][m][2] (fp32 or bf16-packed) -> Wp[m][o][k] = u32(bf16 re, bf16 im).
// Tile: 2 o x 64 k x 128 m via LDS (pad 131: <=2-way conflicts both phases).
__global__ __launch_bounds__(256)
void repack_w(const void* __restrict__ w, u32* __restrict__ Wp,
              const int* __restrict__ flag) {
  __shared__ u32 L[128 * 131];
  const int tid = threadIdx.x;
  const int o0 = blockIdx.x * 2;
  const int k0 = blockIdx.y * 64;
  const int mode = flag[0];
  {
    const int row = tid >> 1, h = tid & 1;      // row = o_l*64 + k_l
    const int o_l = row >> 6, k_l = row & 63;
    if (mode == 0) {
      const float* src = (const float*)w +
          (((size_t)(o0 + o_l) * 256 + (k0 + k_l)) * 128 + h * 64) * 2;
#pragma unroll
      for (int mm = 0; mm < 64; ++mm) {
        float2 f = *(const float2*)(src + mm * 2);
        L[row * 131 + h * 64 + mm] = (u32)f2b(f.x) | ((u32)f2b(f.y) << 16);
      }
    } else {
      const u32* src = (const u32*)w +
          ((size_t)(o0 + o_l) * 256 + (k0 + k_l)) * 128 + h * 64;
#pragma unroll
      for (int mm = 0; mm < 64; ++mm)
        L[row * 131 + h * 64 + mm] = src[mm];
    }
  }
  __syncthreads();
  {
    const int m = tid >> 1, o_l = tid & 1;
    u32* dst = Wp + ((size_t)m * 256 + o0 + o_l) * 256 + k0;
#pragma unroll
    for (int kq = 0; kq < 16; ++kq) {
      u32 v[4];
#pragma unroll
      for (int i = 0; i < 4; ++i)
        v[i] = L[(o_l * 64 + kq * 4 + i) * 131 + m];
      *(uint4*)(dst + kq * 4) = *(const uint4*)v;
    }
  }
}

// ---------------------------------------------------------------- GEMM (NT)
// C = A(MxK,row,lda) * Bt(NxK,row,ldb)^T.
// EPI=1: radix-2 inverse. K=256: kt<128 -> accE, kt>=128 -> accO.
//        Epilogue butterfly: out[t']=x+lrelu(E+O), out[t'+2048]=x+lrelu(E-O).
// EPI=2: radix-2 forward: p=blockIdx.z parity; A-load folds x[t] +/- x[t+2048];
//        pack C into mode-major Xm[m][b][i] = u32(re,im), m = 2j+p.
template <int BM, int BN, int EPI, bool ADUAL>
__global__ __launch_bounds__(256)
void gemm_nt(const void* __restrict__ A, const u16* __restrict__ Bt,
             int K, int lda, int ldb,
             u32* __restrict__ Xp, int ldc,
             const void* __restrict__ xres, void* __restrict__ outp,
             const int* __restrict__ flag) {
  constexpr int LD = 72;                 // 64+8 pad: <=2-way LDS conflicts (free)
  constexpr int FM = BM / 32;
  constexpr int FN = BN / 32;
  __shared__ __align__(16) char smem[(BM + BN) * LD * 2];
  u16* As = (u16*)smem;
  u16* Bs = (u16*)(smem + BM * LD * 2);
  const int mode = (ADUAL || EPI == 1) ? flag[0] : 1;
  const int tid = threadIdx.x;
  const int bn0 = blockIdx.x * BN;
  const int bm0 = blockIdx.y * BM;
  const int lane = tid & 63;
  const int wave = tid >> 6;
  const int wm = wave >> 1, wn = wave & 1;
  const int l15 = lane & 15, q4 = lane >> 4;

  const u16* Btb = Bt;
  if constexpr (EPI == 2) Btb += (size_t)blockIdx.z * BN * ldb;

  f32x4 acc[FM][FN] = {};    // EPI==1: even-mode accumulator E
  f32x4 acc2[FM][FN] = {};   // EPI==1: odd-mode accumulator O (else unused/DCE)

  // one 64-wide K-step of MFMAs into the given accumulator (static indexing)
  auto kstep = [&](f32x4 (&ac)[FM][FN]) {
#pragma unroll
    for (int kk = 0; kk < 2; ++kk) {
      const int ko = kk * 32 + q4 * 8;
      bf16x8 af[FM], bfr[FN];
#pragma unroll
      for (int mi = 0; mi < FM; ++mi)
        af[mi] = *(const bf16x8*)&As[(wm * (BM / 2) + mi * 16 + l15) * LD + ko];
#pragma unroll
      for (int ni = 0; ni < FN; ++ni)
        bfr[ni] = *(const bf16x8*)&Bs[(wn * (BN / 2) + ni * 16 + l15) * LD + ko];
#pragma unroll
      for (int mi = 0; mi < FM; ++mi)
#pragma unroll
        for (int ni = 0; ni < FN; ++ni)
          ac[mi][ni] = __builtin_amdgcn_mfma_f32_16x16x32_bf16(
              af[mi], bfr[ni], ac[mi][ni], 0, 0, 0);
    }
  };

  for (int kt = 0; kt < K; kt += 64) {
    __syncthreads();
    if constexpr (EPI == 2) {
      // radix-2 fold: a = x[row][kt+c] +/- x[row][kt+2048+c]
      const int neg = blockIdx.z;
#pragma unroll
      for (int q = tid; q < BM * 8; q += 256) {
        int row = q >> 3, c8 = q & 7;
        u16 tmp[8];
        if (mode == 1) {
          const u16* s0 = &((const u16*)A)[(size_t)(bm0 + row) * lda + kt + c8 * 8];
          uint4 a0 = *(const uint4*)s0;
          uint4 a1 = *(const uint4*)(s0 + 2048);
          u32 aw[4] = {a0.x, a0.y, a0.z, a0.w};
          u32 bw[4] = {a1.x, a1.y, a1.z, a1.w};
#pragma unroll
          for (int j = 0; j < 4; ++j) {
            float lo = neg ? (blo(aw[j]) - blo(bw[j])) : (blo(aw[j]) + blo(bw[j]));
            float hi = neg ? (bhi(aw[j]) - bhi(bw[j])) : (bhi(aw[j]) + bhi(bw[j]));
            tmp[2 * j]     = f2b(lo);
            tmp[2 * j + 1] = f2b(hi);
          }
        } else {
          const float* s0 = &((const float*)A)[(size_t)(bm0 + row) * lda + kt + c8 * 8];
          float4 f0 = *(const float4*)s0;
          float4 f1 = *(const float4*)(s0 + 4);
          float4 g0 = *(const float4*)(s0 + 2048);
          float4 g1 = *(const float4*)(s0 + 2052);
          float a[8] = {f0.x, f0.y, f0.z, f0.w, f1.x, f1.y, f1.z, f1.w};
          float b[8] = {g0.x, g0.y, g0.z, g0.w, g1.x, g1.y, g1.z, g1.w};
#pragma unroll
          for (int j = 0; j < 8; ++j)
            tmp[j] = f2b(neg ? (a[j] - b[j]) : (a[j] + b[j]));
        }
        *(uint4*)&As[row * LD + c8 * 8] = *(const uint4*)tmp;
      }
    } else {
      const u16* Ab = (const u16*)A;
#pragma unroll
      for (int q = tid; q < BM * 8; q += 256) {
        int row = q >> 3, c8 = q & 7;
        *(uint4*)&As[row * LD + c8 * 8] =
            *(const uint4*)&Ab[(size_t)(bm0 + row) * lda + kt + c8 * 8];
      }
    }
#pragma unroll
    for (int q = tid; q < BN * 8; q += 256) {
      int row = q >> 3, c8 = q & 7;
      *(uint4*)&Bs[row * LD + c8 * 8] =
          *(const uint4*)&Btb[(size_t)(bn0 + row) * ldb + kt + c8 * 8];
    }
    __syncthreads();
    if constexpr (EPI == 1) {
      if (kt >= 128) kstep(acc2); else kstep(acc);
    } else {
      kstep(acc);
    }
  }

  // --------------- epilogues (smem reused; As/Bs dead after barrier) -------
  if constexpr (EPI == 1) {
    // acc rows: wm*64+mi*16+q4*4+r ; cols: wn*32+ni*16+l15 (BN=64).
    // Butterfly: col t'=bn0+cc gets E+O, col bn0+2048+cc gets E-O.
    float* Cs = (float*)smem;            // [32][136]: 0..67 sum, 68..135 diff
    const int s = tid >> 3;              // 0..31 staged row
    const int c8 = tid & 7;
#pragma unroll
    for (int mi = 0; mi < FM; ++mi) {
      __syncthreads();
#pragma unroll
      for (int ni = 0; ni < FN; ++ni) {
        float* dst = &Cs[(wm * 16 + q4 * 4) * 136 + wn * 32 + ni * 16 + l15];
#pragma unroll
        for (int r = 0; r < 4; ++r) {
          float e = acc[mi][ni][r], o = acc2[mi][ni][r];
          dst[r * 136]      = e + o;
          dst[r * 136 + 68] = e - o;
        }
      }
      __syncthreads();
      const int gr = bm0 + mi * 16 + s + ((s < 16) ? 0 : (BM / 2 - 16));
      if (mode == 1) {
        const u16* xr16 = (const u16*)xres;
        u16* o16 = (u16*)outp;
#pragma unroll
        for (int h = 0; h < 2; ++h) {
          float4 va = *(const float4*)&Cs[s * 136 + h * 68 + c8 * 8];
          float4 vb = *(const float4*)&Cs[s * 136 + h * 68 + c8 * 8 + 4];
          size_t gidx = (size_t)gr * ldc + bn0 + h * 2048 + c8 * 8;
          uint4 xv = *(const uint4*)&xr16[gidx];
          float cv[8] = {va.x, va.y, va.z, va.w, vb.x, vb.y, vb.z, vb.w};
          u32 xw[4] = {xv.x, xv.y, xv.z, xv.w};
          u16 ov[8];
#pragma unroll
          for (int j = 0; j < 4; ++j) {
            float l0 = cv[2 * j]     >= 0.f ? cv[2 * j]     : 0.2f * cv[2 * j];
            float l1 = cv[2 * j + 1] >= 0.f ? cv[2 * j + 1] : 0.2f * cv[2 * j + 1];
            ov[2 * j]     = f2b(blo(xw[j]) + l0);
            ov[2 * j + 1] = f2b(bhi(xw[j]) + l1);
          }
          *(uint4*)&o16[gidx] = *(const uint4*)ov;
        }
      } else {
        const float* xf = (const float*)xres;
        float* of = (float*)outp;
#pragma unroll
        for (int h = 0; h < 2; ++h) {
          float4 v0 = *(const float4*)&Cs[s * 136 + h * 68 + c8 * 8];
          float4 v1 = *(const float4*)&Cs[s * 136 + h * 68 + c8 * 8 + 4];
          size_t gidx = (size_t)gr * ldc + bn0 + h * 2048 + c8 * 8;
          float4 x0 = *(const float4*)&xf[gidx];
          float4 x1 = *(const float4*)&xf[gidx + 4];
          float4 o0, o1;
          o0.x = x0.x + (v0.x >= 0.f ? v0.x : 0.2f * v0.x);
          o0.y = x0.y + (v0.y >= 0.f ? v0.y : 0.2f * v0.y);
          o0.z = x0.z + (v0.z >= 0.f ? v0.z : 0.2f * v0.z);
          o0.w = x0.w + (v0.w >= 0.f ? v0.w : 0.2f * v0.w);
          o1.x = x1.x + (v1.x >= 0.f ? v1.x : 0.2f * v1.x);
          o1.y = x1.y + (v1.y >= 0.f ? v1.y : 0.2f * v1.y);
          o1.z = x1.z + (v1.z >= 0.f ? v1.z : 0.2f * v1.z);
          o1.w = x1.w + (v1.w >= 0.f ? v1.w : 0.2f * v1.w);
          *(float4*)&of[gidx] = o0;
          *(float4*)&of[gidx + 4] = o1;
        }
      }
    }
  } else {
    // EPI==2: BM=32 (FM=1), BN=128. Ls cols c<64 -> Re(mode 2c+p), c>=64 -> Im.
    // Write mode-major: Xm[m=2j+p][b][ic0+ic] = u32(re,im).
    constexpr int LP = 136;              // 128+8 pad
    u16* Ls = (u16*)smem;                // [32][136] bf16 tile
    __syncthreads();
#pragma unroll
    for (int ni = 0; ni < FN; ++ni) {
      u16* dst = &Ls[(wm * 16 + q4 * 4) * LP + wn * 64 + ni * 16 + l15];
#pragma unroll
      for (int r = 0; r < 4; ++r) dst[r * LP] = f2b(acc[0][ni][r]);
    }
    __syncthreads();
    const int b   = bm0 >> 8;
    const int ic0 = bm0 & 255;
    const int j   = tid >> 2;            // 0..63
    const int icg = tid & 3;             // ic block of 8
    const int mo  = 2 * j + blockIdx.z;
    u32 vals[8];
#pragma unroll
    for (int ii = 0; ii < 8; ++ii) {
      int ic = icg * 8 + ii;
      vals[ii] = (u32)Ls[ic * LP + j] | ((u32)Ls[ic * LP + 64 + j] << 16);
    }
    u32* dst = &Xp[((size_t)mo * 32 + b) * 256 + ic0 + icg * 8];
    *(uint4*)dst       = *(const uint4*)&vals[0];
    *(uint4*)(dst + 4) = *(const uint4*)&vals[4];
  }
}

// ---------------------------------------------------------------- mode mix (MFMA)
// Per block: one (mode m, o-quarter). M=32 b, N=64 o, K=256 ic.
// Yre = Xre*Wre + Xim*(-Wim); Yim = Xre*Wim + Xim*Wre (fp32 MFMA accum).
// X staged once (bf16 Xre/Xim, stride 266: conflict-free MFMA reads);
// W streamed per K-chunk of 32 from Wp[m] (contiguous). -Wim via VALU XOR.
__global__ __launch_bounds__(256)
void mixm_kernel(const u32* __restrict__ Xm, const u32* __restrict__ Wp,
                 u16* __restrict__ Yp) {
  constexpr int XL = 266;   // u16 row stride (133 words: gcd(5,32)=1)
  constexpr int WL = 40;    // u16 row stride, W arrays [64][32]
  __shared__ u16 Xre[32 * XL];
  __shared__ u16 Xim[32 * XL];
  __shared__ u16 Wre[64 * WL];
  __shared__ u16 Wip[64 * WL];
  const int tid = threadIdx.x;
  const int m  = blockIdx.x;            // mode 0..127
  const int o0 = blockIdx.y * 64;       // o-range base
  const int lane = tid & 63, wv = tid >> 6;
  const int l15 = lane & 15, q4 = lane >> 4;

  // ---- stage X once: Xm[m][b][i] u32(re,im), 32x256 -> Xre/Xim bf16
  {
    const int b = tid >> 3, i0 = (tid & 7) * 32;
    const uint4* src = (const uint4*)(Xm + ((size_t)m * 32 + b) * 256 + i0);
#pragma unroll
    for (int c = 0; c < 8; ++c) {
      uint4 v = src[c];
      int i = i0 + c * 4;
      *(u32*)&Xre[b * XL + i]     = (v.x & 0xffffu) | (v.y << 16);
      *(u32*)&Xre[b * XL + i + 2] = (v.z & 0xffffu) | (v.w << 16);
      *(u32*)&Xim[b * XL + i]     = (v.x >> 16) | (v.y & 0xffff0000u);
      *(u32*)&Xim[b * XL + i + 2] = (v.z >> 16) | (v.w & 0xffff0000u);
    }
  }

  f32x4 accRe[2] = {}, accIm[2] = {};

  const int so = tid >> 2;              // staging o 0..63
  const int sk = (tid & 3) * 8;         // staging k base

  for (int kt = 0; kt < 8; ++kt) {
    const int k0 = kt * 32;
    __syncthreads();
    // ---- stage W chunk [64 o][32 k] from Wp[m] (contiguous 8 u32 / thread)
    {
      const u32* wp = Wp + ((size_t)m * 256 + o0 + so) * 256 + k0 + sk;
      uint4 v0 = *(const uint4*)wp;
      uint4 v1 = *(const uint4*)(wp + 4);
      u32 vs[8] = {v0.x, v0.y, v0.z, v0.w, v1.x, v1.y, v1.z, v1.w};
#pragma unroll
      for (int kk = 0; kk < 8; ++kk) {
        Wre[so * WL + sk + kk] = (u16)vs[kk];
        Wip[so * WL + sk + kk] = (u16)(vs[kk] >> 16);
      }
    }
    __syncthreads();
    // ---- MFMA on chunk
    bf16x8 aRe[2], aIm[2];
#pragma unroll
    for (int mi = 0; mi < 2; ++mi) {
      aRe[mi] = *(const bf16x8*)&Xre[(mi * 16 + l15) * XL + k0 + q4 * 8];
      aIm[mi] = *(const bf16x8*)&Xim[(mi * 16 + l15) * XL + k0 + q4 * 8];
    }
    bf16x8 bRe = *(const bf16x8*)&Wre[(wv * 16 + l15) * WL + q4 * 8];
    bf16x8 bIp = *(const bf16x8*)&Wip[(wv * 16 + l15) * WL + q4 * 8];
    u32x4 ipw = *(const u32x4*)&bIp;
    u32x4 inw = ipw ^ 0x80008000u;      // negate both bf16 halves
    bf16x8 bIn = *(const bf16x8*)&inw;
#pragma unroll
    for (int mi = 0; mi < 2; ++mi) {
      accRe[mi] = __builtin_amdgcn_mfma_f32_16x16x32_bf16(aRe[mi], bRe, accRe[mi], 0, 0, 0);
      accRe[mi] = __builtin_amdgcn_mfma_f32_16x16x32_bf16(aIm[mi], bIn, accRe[mi], 0, 0, 0);
      accIm[mi] = __builtin_amdgcn_mfma_f32_16x16x32_bf16(aRe[mi], bIp, accIm[mi], 0, 0, 0);
      accIm[mi] = __builtin_amdgcn_mfma_f32_16x16x32_bf16(aIm[mi], bRe, accIm[mi], 0, 0, 0);
    }
  }

  // ---- epilogue: Yp32[(b*256+o)*128 + (m&1)*64 + (m>>1)] = (re*sRe | im*sIm<<16)
  const float sIm = 2.0f / 4096.0f;
  const float sRe = (m == 0) ? (1.0f / 4096.0f) : (2.0f / 4096.0f);
  u32* Yp32 = (u32*)Yp;
  const int o = o0 + wv * 16 + l15;
  const int word = (m & 1) * 64 + (m >> 1);
#pragma unroll
  for (int mi = 0; mi < 2; ++mi)
#pragma unroll
    for (int r = 0; r < 4; ++r) {
      int b = mi * 16 + q4 * 4 + r;
      u32 val = (u32)f2b(accRe[mi][r] * sRe) | ((u32)f2b(accIm[mi][r] * sIm) << 16);
      Yp32[((size_t)(b * 256 + o)) * 128 + word] = val;
    }
}

// ---------------------------------------------------------------- launch
extern "C" void kernel_launch(void* const* d_in, const int* in_sizes, int n_in,
                              void* d_out, int out_size, void* d_ws, size_t ws_size,
                              hipStream_t stream) {
  const void* x = d_in[0];                // (32,256,4096) fp32 or bf16
  const void* w = d_in[1];                // (256,256,128,2) fp32 or bf16

  char* ws = (char*)d_ws;
  int*  flag  = (int*)(ws);
  u16*  Bas1P = (u16*)(ws + (1u << 20));  // 1 MB  [r=256][t'=2048] fwd parity
  u16*  Bas2P = (u16*)(ws + (2u << 20));  // 1 MB  [t'=2048][c=256] inv parity
  u32*  Xm    = (u32*)(ws + (4u << 20));  // 4 MB  [m][b][i] u32(re,im)
  u16*  Yp    = (u16*)(ws + (8u << 20));  // 4 MB  parity-grouped (re,im)
  u32*  Wp    = (u32*)(ws + (12u << 20)); // 32 MB [m][o][k] u32(re,im)

  probe_kernel<<<dim3(1), dim3(256), 0, stream>>>((const u16*)x, flag);
  basis_kernel<<<dim3(2048), dim3(256), 0, stream>>>(Bas1P, Bas2P);

  // one coalesced pass: W[o][k][m] -> Wp[m][o][k]
  repack_w<<<dim3(128, 4), dim3(256), 0, stream>>>(w, Wp, flag);

  // radix-2 folded forward rDFT: z=parity, K=2048, fused pack into Xm
  gemm_nt<32, 128, 2, true><<<dim3(1, 256, 2), dim3(256), 0, stream>>>(
      x, Bas1P, 2048, MLEN, 2048, Xm, 0, nullptr, nullptr, flag);

  // per-mode MFMA complex channel mix -> Yp (bf16, irfft scaling folded in)
  mixm_kernel<<<dim3(128, 4), dim3(256), 0, stream>>>(Xm, Wp, Yp);

  // radix-2 folded inverse DFT + LeakyReLU + residual (butterfly epilogue)
  gemm_nt<128, 64, 1, false><<<dim3(32, 64, 1), dim3(256), 0, stream>>>(
      Yp, Bas2P, 256, 256, 256, nullptr, MLEN, x, d_out, flag);
}